// Round 15
// baseline (48.209 us; speedup 1.0000x reference)
//
#include <hip/hip_runtime.h>
#include <hip/hip_bf16.h>

#define BB 128
#define FF 12288
#define HH 2048
#define TAU_F 0.1f
#define THR_F 1e-3f
#define NKG (FF / 8)          // 1536 k-groups of 8
#define BH (BB * HH)          // 262144
#define NFLAGS 192            // per-chunk x0-nonzero flags
#define SKD 16                // default split-K

typedef __attribute__((ext_vector_type(4))) float f32x4;
typedef __attribute__((ext_vector_type(8))) short s16x8;
typedef __attribute__((ext_vector_type(8))) unsigned short u16x8;
typedef __attribute__((ext_vector_type(4))) unsigned short u16x4;

// LDS-only drain + barrier in ONE asm: nothing is reordered across it, but
// in-flight global loads are NOT drained.
__device__ __forceinline__ void barrier_lds() {
    asm volatile("s_waitcnt lgkmcnt(0)\ns_barrier" ::: "memory");
}

// bf16 split via scalar casts: compiler pairs these into v_cvt_pk_bf16_f32.
__device__ __forceinline__ void bsplit(float v, unsigned short& h, unsigned short& l) {
    const __hip_bfloat16 bh = __float2bfloat16(v);
    const float hf = __bfloat162float(bh);
    const __hip_bfloat16 bl = __float2bfloat16(v - hf);
    h = __builtin_bit_cast(unsigned short, bh);
    l = __builtin_bit_cast(unsigned short, bl);
}

// Wave-uniform OR over the 192 flag ints (48 int4 loads across lanes 0..47).
__device__ __forceinline__ bool read_nz(const int* __restrict__ flags) {
    const int lane = threadIdx.x & 63;
    int v = 0;
    if (lane < NFLAGS / 4) {
        const int4 q = ((const int4*)flags)[lane];
        v = q.x | q.y | q.z | q.w;
    }
    return __any(v != 0);
}

// Presplit one 8-kg chunk (i in [0,192)) of X into frag-ordered hi/lo.
__device__ __forceinline__ void presplit_blk(
    const float* __restrict__ X, unsigned short* __restrict__ AH,
    unsigned short* __restrict__ AL, int i, int t) {
    const int kg = i * 8 + (t & 7);
#pragma unroll
    for (int r = 0; r < 4; ++r) {
        const int m = (t >> 3) + r * 32;
        const float* src = X + (size_t)m * FF + kg * 8;
        u16x8 hv, lv;
#pragma unroll
        for (int j = 0; j < 8; ++j) {
            unsigned short h, lo;
            bsplit(src[j], h, lo);
            hv[j] = h; lv[j] = lo;
        }
        const size_t o = ((size_t)kg * BB + m) * 8;
        *(u16x8*)(AH + o) = hv;
        *(u16x8*)(AL + o) = lv;
    }
}

// ---------------------------------------------------------------------------
// Presplit. z=0: x always. z=1: compute+write per-chunk flag; write x0 splits
// only if own chunk is nonzero (gemm zero-masks unwritten chunks).
__global__ __launch_bounds__(256) void presplit_kernel(
    const float* __restrict__ x, const float* __restrict__ x0,
    unsigned short* __restrict__ Ah, unsigned short* __restrict__ Al,
    int* __restrict__ flags) {
    const int z = blockIdx.y;
    const int i = blockIdx.x;
    const int t = threadIdx.x;
    if (z == 0) {
        presplit_blk(x, Ah, Al, i, t);
        return;
    }
    // z == 1: flag pass (32 KB chunk, L1-hot for the optional second pass)
    __shared__ int snz[4];
    const int w = t >> 6, lane = t & 63;
    const int kg = i * 8 + (t & 7);
    int tnz = 0;
#pragma unroll
    for (int r = 0; r < 4; ++r) {
        const int m = (t >> 3) + r * 32;
        const float4* src = (const float4*)(x0 + (size_t)m * FF + kg * 8);
        const float4 a = src[0], b = src[1];
        tnz |= (a.x != 0.f) | (a.y != 0.f) | (a.z != 0.f) | (a.w != 0.f)
             | (b.x != 0.f) | (b.y != 0.f) | (b.z != 0.f) | (b.w != 0.f);
    }
    const int wnz = __any(tnz != 0) ? 1 : 0;
    if (lane == 0) snz[w] = wnz;
    __syncthreads();
    const int bnz = snz[0] | snz[1] | snz[2] | snz[3];
    if (t == 0) flags[i] = bnz;
    if (bnz) {
        const size_t zoff = (size_t)NKG * BB * 8;
        presplit_blk(x0, Ah + zoff, Al + zoff, i, t);
    }
}

// ---------------------------------------------------------------------------
// Split-precision MFMA GEMM partials: P[z*SK+kc] = X_z[:, kchunk] @ W1[kchunk, :].
// Tile 128x64, 8 waves (512 threads, 16 rows/wave). 4-buffer LDS (32 KB),
// ONE barrier per 64-K phase: phase(it) computes iters (it,it+1) from bufs
// (it&3,(it+1)&3), writes bufs ((it+2)&3,(it+3)&3), issues loads (it+4,it+5).
// Reads of a buf pair and writes to it are separated by exactly one barrier.
// A reg-direct double-buffered; barrier drains LDS only (global loads fly).
__global__ __launch_bounds__(512, 4) void mfma_gemm_kernel(
    const unsigned short* __restrict__ Ah, const unsigned short* __restrict__ Al,
    const float* __restrict__ W1, float* __restrict__ P,
    const int* __restrict__ flags, int SK, int KC, int NIT) {
    const int z = blockIdx.y;
    if (z == 1 && !read_nz(flags)) return;

    // XCD-aware bijective swizzle (gridDim.x always % 8 == 0 here).
    const int nwg = gridDim.x;
    const int bx  = blockIdx.x;
    const int wg  = (bx & 7) * (nwg >> 3) + (bx >> 3);
    const int ct  = wg & 31;   // column tile (64 cols)
    const int kc  = wg >> 5;   // split-K chunk

    const int t   = threadIdx.x;
    const int w   = t >> 6;    // wave 0..7 (16 rows each)
    const int l   = t & 63;
    const int kgl = l >> 4;    // frag k-group 0..3
    const int li  = l & 15;

    __shared__ unsigned short lds[4][4096];  // [buf][Bh 2048 | Bl 2048]

    const size_t zoffA = (size_t)z * NKG * BB * 8;
    const unsigned short* APH = Ah + zoffA;
    const unsigned short* APL = Al + zoffA;
    const bool zchk = (z == 1);

    f32x4 acc[4];
#pragma unroll
    for (int nt = 0; nt < 4; ++nt) acc[nt] = (f32x4)0.f;

    const int kbase = kc * KC;
    const int kg0   = kbase >> 3;

    s16x8 ahE, alE, ahO, alO;
    auto loadA = [&](s16x8& ah, s16x8& al, int it) {
        const int kg = kg0 + it * 4 + kgl;
        if (zchk && flags[kg >> 3] == 0) {
            ah = (s16x8)0; al = (s16x8)0;
            return;
        }
        const size_t o = ((size_t)kg * BB + w * 16 + li) * 8;
        ah = *(const s16x8*)(APH + o);
        al = *(const s16x8*)(APL + o);
    };

    // B staging: thread t owns rows w*4..w*4+3 (k within chunk), col l.
    auto stageB_load = [&](int it, float* v) {
        const float* src = W1 + (size_t)(kbase + it * 32 + w * 4) * HH + ct * 64 + l;
#pragma unroll
        for (int j = 0; j < 4; ++j) v[j] = src[(size_t)j * HH];
    };
    // LDS element layout [kg 0..3][col 0..63][kin 0..7]; this thread's 4
    // values land contiguously: kg = w>>1, kin = (w&1)*4 + j.
    auto stageB_write = [&](int buf, const float* v) {
        u16x4 hv, lv;
#pragma unroll
        for (int j = 0; j < 4; ++j) {
            unsigned short h, lo;
            bsplit(v[j], h, lo);
            hv[j] = h; lv[j] = lo;
        }
        unsigned short* d = &lds[buf][(((w >> 1) * 64 + l) * 8) + (w & 1) * 4];
        *(u16x4*)(d)        = hv;
        *(u16x4*)(d + 2048) = lv;
    };
    auto computeR = [&](const s16x8& ah, const s16x8& al, int buf) {
        const unsigned short* L = lds[buf];
#pragma unroll
        for (int nt = 0; nt < 4; ++nt) {
            const int no = (kgl * 64 + nt * 16 + li) * 8;
            const s16x8 fbh = *(const s16x8*)&L[no];
            const s16x8 fbl = *(const s16x8*)&L[2048 + no];
            acc[nt] = __builtin_amdgcn_mfma_f32_16x16x32_bf16(ah, fbh, acc[nt], 0, 0, 0);
            acc[nt] = __builtin_amdgcn_mfma_f32_16x16x32_bf16(ah, fbl, acc[nt], 0, 0, 0);
            acc[nt] = __builtin_amdgcn_mfma_f32_16x16x32_bf16(al, fbh, acc[nt], 0, 0, 0);
        }
    };

    // Prologue: A(0); B(0),B(1) staged to buf0,buf1; B(2),B(3) in reg slots.
    float bv0[4], bv1[4], bv2[4], bv3[4];
    loadA(ahE, alE, 0);
    stageB_load(0, bv0);
    stageB_write(0, bv0);
    stageB_load(1, bv1);
    stageB_write(1, bv1);
    stageB_load(2, bv2);
    if (NIT > 3) stageB_load(3, bv3);
    barrier_lds();

    // One barrier per 2 iters. Macro phase at base (base%4 == 0 or 2):
    //   issue loads (base+4, base+5) into the slots freed 2 phases ago,
    //   loadA(base+1) -> O, compute(base) [E, buf base&3],
    //   write buf (base+2)&3, loadA(base+2) -> E,
    //   compute(base+1) [O, buf (base+1)&3], write buf (base+3)&3, barrier.
    // NIT divisible by 4 for all SK in {16,8,4,2,1}.
#define GPH(base, sA, sB, sC, sD, b0, b1, b2, b3)                             \
    {                                                                         \
        if ((base) + 4 < NIT) stageB_load((base) + 4, sA);                    \
        if ((base) + 5 < NIT) stageB_load((base) + 5, sB);                    \
        if ((base) + 1 < NIT) loadA(ahO, alO, (base) + 1);                    \
        computeR(ahE, alE, b0);                                               \
        if ((base) + 2 < NIT) { stageB_write(b2, sC); loadA(ahE, alE, (base) + 2); } \
        if ((base) + 1 < NIT) computeR(ahO, alO, b1);                         \
        if ((base) + 3 < NIT) stageB_write(b3, sD);                           \
        barrier_lds();                                                        \
    }

    for (int it = 0; it < NIT; it += 4) {
        GPH(it,     bv0, bv1, bv2, bv3, 0, 1, 2, 3)
        GPH(it + 2, bv2, bv3, bv0, bv1, 2, 3, 0, 1)
    }
#undef GPH

    float* dst = P + (size_t)(z * SK + kc) * BH;
    const int r0 = w * 16 + (l >> 4) * 4;
    const int c0 = ct * 64 + li;
#pragma unroll
    for (int nt = 0; nt < 4; ++nt)
#pragma unroll
        for (int r = 0; r < 4; ++r)
            dst[(size_t)(r0 + r) * HH + c0 + nt * 16] = acc[nt][r];
}

// ---------------------------------------------------------------------------
// Scalar deterministic bisect for the linear (x0==0) case: f(c) = c*S - tau.
__device__ __forceinline__ void solve_linear(float S, float& c, bool& done) {
    const bool inside = (S - TAU_F <= 0.f);
    float a = 0.f, bh = 1.f;
    c = 1.f; done = inside;
    for (int it = 0; it < 30; ++it) {
        const float cm = 0.5f * (a + bh);
        const float v = cm * S - TAU_F;
        const bool upd  = !done;
        const bool hit  = upd && (v >= -THR_F) && (v < 0.f);
        const bool go_a = upd && (v < 0.f) && !hit;
        const bool go_b = upd && (v >= 0.f);
        a  = go_a ? cm : a;
        bh = go_b ? cm : bh;
        c  = upd  ? cm : c;
        done = done || hit;
    }
    c = inside ? 1.f : c;
}

// ---------------------------------------------------------------------------
// Fused tail, redundant-solve wide: 256 blocks x 512 threads. Block i owns
// sample b = i>>1 and half-row (i&1). Both blocks of a sample compute the
// IDENTICAL fixed-order reduction -> identical c (deterministic); each writes
// its half-row. Doubles the P read, but P is L3-hot; all 256 CUs busy.
__global__ __launch_bounds__(512) void bisect_write_kernel(
    const float* __restrict__ P, const float* __restrict__ w2,
    const float* __restrict__ x, const float* __restrict__ x0,
    const int* __restrict__ flags, float* __restrict__ out, int SK) {
    const int b    = blockIdx.x >> 1;
    const int half = blockIdx.x & 1;
    const int t = threadIdx.x;
    const int w = t >> 6;
    const int lane = t & 63;
    __shared__ float red[8];
    const bool nz = read_nz(flags);

    // Fixed-order split-K reduce: thread t owns 4 h-cols (one float4).
    const f32x4* P1 = (const f32x4*)(P + (size_t)b * HH) + t;
    f32x4 u1 = (f32x4)0.f;
    for (int kc = 0; kc < SK; ++kc) {           // fixed order: deterministic
        const f32x4 v = P1[(size_t)kc * (BH / 4)];
        u1.x += v.x; u1.y += v.y; u1.z += v.z; u1.w += v.w;
    }
    const f32x4 wv = ((const f32x4*)w2)[t];

    auto blockReduce = [&](float v) -> float {
#pragma unroll
        for (int off = 32; off > 0; off >>= 1) v += __shfl_xor(v, off);
        if (lane == 0) red[w] = v;
        __syncthreads();
        float s = 0.f;
#pragma unroll
        for (int i = 0; i < 8; ++i) s += red[i];   // fixed order, uniform
        __syncthreads();
        return s;
    };

    float c = 1.f;
    bool done = false;
    if (!nz) {
        float p = fmaxf(u1.x, 0.f) * wv.x;
        p = fmaf(fmaxf(u1.y, 0.f), wv.y, p);
        p = fmaf(fmaxf(u1.z, 0.f), wv.z, p);
        p = fmaf(fmaxf(u1.w, 0.f), wv.w, p);
        const float S = blockReduce(p);
        solve_linear(S, c, done);
    } else {
        const f32x4* P0 = (const f32x4*)(P + (size_t)(SK * BH) + (size_t)b * HH) + t;
        f32x4 u0 = (f32x4)0.f;
        for (int kc = 0; kc < SK; ++kc) {
            const f32x4 v = P0[(size_t)kc * (BH / 4)];
            u0.x += v.x; u0.y += v.y; u0.z += v.z; u0.w += v.w;
        }
        f32x4 dd;
        dd.x = u1.x - u0.x; dd.y = u1.y - u0.y;
        dd.z = u1.z - u0.z; dd.w = u1.w - u0.w;
        auto feval = [&](float cc) -> float {
            float p = fmaxf(fmaf(cc, dd.x, u0.x), 0.f) * wv.x;
            p = fmaf(fmaxf(fmaf(cc, dd.y, u0.y), 0.f), wv.y, p);
            p = fmaf(fmaxf(fmaf(cc, dd.z, u0.z), 0.f), wv.z, p);
            p = fmaf(fmaxf(fmaf(cc, dd.w, u0.w), 0.f), wv.w, p);
            return blockReduce(p) - TAU_F;
        };
        const float f1 = feval(1.f);
        const bool inside = (f1 <= 0.f);
        float a = 0.f, bh = 1.f;
        done = inside;
        for (int it = 0; it < 30; ++it) {
            const float cm = 0.5f * (a + bh);
            const float v = feval(cm);
            const bool upd  = !done;
            const bool hit  = upd && (v >= -THR_F) && (v < 0.f);
            const bool go_a = upd && (v < 0.f) && !hit;
            const bool go_b = upd && (v >= 0.f);
            a  = go_a ? cm : a;
            bh = go_b ? cm : bh;
            c  = upd  ? cm : c;
            done = done || hit;
        }
        c = inside ? 1.f : c;
    }

    // Write half-row (uniform branches). Half = 1536 f4; 512 thr x 3 f4.
    const float nanv = __int_as_float(0x7fc00000);
    const int base = half * 1536;
    const float4* xr  = (const float4*)(x  + (size_t)b * FF) + base;
    const float4* x0r = (const float4*)(x0 + (size_t)b * FF) + base;
    float4* orow = (float4*)(out + (size_t)b * FF) + base;
    if (!done) {
        float4 o; o.x = o.y = o.z = o.w = nanv;
#pragma unroll
        for (int k2 = 0; k2 < 3; ++k2) orow[t + 512 * k2] = o;
    } else if (!nz) {
#pragma unroll
        for (int k2 = 0; k2 < 3; ++k2) {
            const int i = t + 512 * k2;
            float4 xv = xr[i], o;
            o.x = c * xv.x; o.y = c * xv.y; o.z = c * xv.z; o.w = c * xv.w;
            orow[i] = o;
        }
    } else {
#pragma unroll
        for (int k2 = 0; k2 < 3; ++k2) {
            const int i = t + 512 * k2;
            float4 xv = xr[i], zv = x0r[i], o;
            o.x = fmaf(c, xv.x - zv.x, zv.x);
            o.y = fmaf(c, xv.y - zv.y, zv.y);
            o.z = fmaf(c, xv.z - zv.z, zv.z);
            o.w = fmaf(c, xv.w - zv.w, zv.w);
            orow[i] = o;
        }
    }
}

// ---------------------------------------------------------------------------
// Fallback path helpers (small workspace only).
__global__ __launch_bounds__(256) void zflags_kernel(
    const float4* __restrict__ x0, int* __restrict__ flags) {
    const int t = threadIdx.x;
    const int w = t >> 6, lane = t & 63;
    __shared__ int snz[4];
    int tnz = 0;
    const int base = blockIdx.x * 2048 + t;
#pragma unroll
    for (int j = 0; j < 8; ++j) {
        float4 v = x0[base + 256 * j];
        tnz |= (v.x != 0.f) | (v.y != 0.f) | (v.z != 0.f) | (v.w != 0.f);
    }
    const int wnz = __any(tnz != 0) ? 1 : 0;
    if (lane == 0) snz[w] = wnz;
    __syncthreads();
    if (t == 0) flags[blockIdx.x] = snz[0] | snz[1] | snz[2] | snz[3];
}

__global__ __launch_bounds__(256) void legacy_gemm_kernel(
    const float* __restrict__ x, const float* __restrict__ x0,
    const float* __restrict__ W1, float* __restrict__ P,
    const int* __restrict__ flags) {
    const int ct = blockIdx.x, z = blockIdx.z, t = threadIdx.x;
    if (z == 1 && !read_nz(flags)) return;
    const int cg = t & 7, rg = t >> 3;
    const int r0 = rg * 4, cc = ct * 64 + cg * 8;
    float acc[4][8];
#pragma unroll
    for (int i = 0; i < 4; ++i)
#pragma unroll
        for (int n = 0; n < 8; ++n) acc[i][n] = 0.f;
    const float* __restrict__ X = z ? x0 : x;
    for (int k = 0; k < FF; k += 4) {
        float xr[4][4];
#pragma unroll
        for (int i = 0; i < 4; ++i) {
            float4 v = *(const float4*)(X + (size_t)(r0 + i) * FF + k);
            xr[i][0] = v.x; xr[i][1] = v.y; xr[i][2] = v.z; xr[i][3] = v.w;
        }
        float wr[4][8];
#pragma unroll
        for (int j = 0; j < 4; ++j) {
            float4 a = *(const float4*)(W1 + (size_t)(k + j) * HH + cc);
            float4 b = *(const float4*)(W1 + (size_t)(k + j) * HH + cc + 4);
            wr[j][0] = a.x; wr[j][1] = a.y; wr[j][2] = a.z; wr[j][3] = a.w;
            wr[j][4] = b.x; wr[j][5] = b.y; wr[j][6] = b.z; wr[j][7] = b.w;
        }
#pragma unroll
        for (int j = 0; j < 4; ++j)
#pragma unroll
            for (int i = 0; i < 4; ++i)
#pragma unroll
                for (int n = 0; n < 8; ++n)
                    acc[i][n] = fmaf(xr[i][j], wr[j][n], acc[i][n]);
    }
    float* Pp = P + (size_t)z * BH;
#pragma unroll
    for (int i = 0; i < 4; ++i) {
        float4 o0, o1;
        o0.x = acc[i][0]; o0.y = acc[i][1]; o0.z = acc[i][2]; o0.w = acc[i][3];
        o1.x = acc[i][4]; o1.y = acc[i][5]; o1.z = acc[i][6]; o1.w = acc[i][7];
        *(float4*)(Pp + (size_t)(r0 + i) * HH + cc) = o0;
        *(float4*)(Pp + (size_t)(r0 + i) * HH + cc + 4) = o1;
    }
}

// ---------------------------------------------------------------------------
extern "C" void kernel_launch(void* const* d_in, const int* in_sizes, int n_in,
                              void* d_out, int out_size, void* d_ws, size_t ws_size,
                              hipStream_t stream) {
    const float* x0 = (const float*)d_in[0];
    const float* x  = (const float*)d_in[1];
    const float* W1 = (const float*)d_in[2];
    const float* w2 = (const float*)d_in[3];
    float* out = (float*)d_out;
    char* ws = (char*)d_ws;

    // ws: Ah | Al | flags(1KB) | P[2*SK][B][H]
    const size_t szA   = (size_t)2 * NKG * BB * 8 * sizeof(unsigned short); // 6291456
    const size_t offAl = szA;
    const size_t offFl = 2 * szA;
    const size_t offP  = offFl + 1024;

    int SK = 0;
    const int cand[5] = {SKD, 8, 4, 2, 1};   // NIT = FF/SK/32 divisible by 4 for all
    for (int i = 0; i < 5; ++i) {
        const size_t need = offP + (size_t)2 * cand[i] * BH * sizeof(float);
        if (ws_size >= need) { SK = cand[i]; break; }
    }

    if (SK > 0) {
        unsigned short* Ah = (unsigned short*)ws;
        unsigned short* Al = (unsigned short*)(ws + offAl);
        int*   flags = (int*)(ws + offFl);
        float* P     = (float*)(ws + offP);
        const int KC = FF / SK, NIT = KC / 32;

        presplit_kernel<<<dim3(NFLAGS, 2), 256, 0, stream>>>(x, x0, Ah, Al, flags);
        mfma_gemm_kernel<<<dim3(32 * SK, 2), 512, 0, stream>>>(Ah, Al, W1, P, flags, SK, KC, NIT);
        bisect_write_kernel<<<2 * BB, 512, 0, stream>>>(P, w2, x, x0, flags, out, SK);
    } else {
        // Low-memory fallback: fp32 VALU GEMM, SK=1 layout.
        float* P     = (float*)ws;
        int*   flags = (int*)(ws + (size_t)2 * BH * sizeof(float));
        zflags_kernel<<<NFLAGS, 256, 0, stream>>>((const float4*)x0, flags);
        legacy_gemm_kernel<<<dim3(32, 1, 2), 256, 0, stream>>>(x, x0, W1, P, flags);
        bisect_write_kernel<<<2 * BB, 512, 0, stream>>>(P, w2, x, x0, flags, out, 1);
    }
}

// Round 16
// 46.237 us; speedup vs baseline: 1.0426x; 1.0426x over previous
//
#include <hip/hip_runtime.h>
#include <hip/hip_bf16.h>

#define BB 128
#define FF 12288
#define HH 2048
#define TAU_F 0.1f
#define THR_F 1e-3f
#define NKG (FF / 8)          // 1536 k-groups of 8
#define BH (BB * HH)          // 262144
#define NFLAGS 192            // per-chunk x0-nonzero flags
#define SKD 16                // default split-K

typedef __attribute__((ext_vector_type(4))) float f32x4;
typedef __attribute__((ext_vector_type(8))) short s16x8;
typedef __attribute__((ext_vector_type(8))) unsigned short u16x8;
typedef __attribute__((ext_vector_type(4))) unsigned short u16x4;

// LDS-only drain + barrier in ONE asm: nothing is reordered across it, but
// in-flight global loads are NOT drained.
__device__ __forceinline__ void barrier_lds() {
    asm volatile("s_waitcnt lgkmcnt(0)\ns_barrier" ::: "memory");
}

// bf16 split via scalar casts: compiler pairs these into v_cvt_pk_bf16_f32.
__device__ __forceinline__ void bsplit(float v, unsigned short& h, unsigned short& l) {
    const __hip_bfloat16 bh = __float2bfloat16(v);
    const float hf = __bfloat162float(bh);
    const __hip_bfloat16 bl = __float2bfloat16(v - hf);
    h = __builtin_bit_cast(unsigned short, bh);
    l = __builtin_bit_cast(unsigned short, bl);
}

// Wave-uniform OR over the 192 flag ints (48 int4 loads across lanes 0..47).
__device__ __forceinline__ bool read_nz(const int* __restrict__ flags) {
    const int lane = threadIdx.x & 63;
    int v = 0;
    if (lane < NFLAGS / 4) {
        const int4 q = ((const int4*)flags)[lane];
        v = q.x | q.y | q.z | q.w;
    }
    return __any(v != 0);
}

// Presplit one 8-kg chunk (i in [0,192)) of X into frag-ordered hi/lo.
__device__ __forceinline__ void presplit_blk(
    const float* __restrict__ X, unsigned short* __restrict__ AH,
    unsigned short* __restrict__ AL, int i, int t) {
    const int kg = i * 8 + (t & 7);
#pragma unroll
    for (int r = 0; r < 4; ++r) {
        const int m = (t >> 3) + r * 32;
        const float* src = X + (size_t)m * FF + kg * 8;
        u16x8 hv, lv;
#pragma unroll
        for (int j = 0; j < 8; ++j) {
            unsigned short h, lo;
            bsplit(src[j], h, lo);
            hv[j] = h; lv[j] = lo;
        }
        const size_t o = ((size_t)kg * BB + m) * 8;
        *(u16x8*)(AH + o) = hv;
        *(u16x8*)(AL + o) = lv;
    }
}

// ---------------------------------------------------------------------------
// Presplit. z=0: x always. z=1: compute+write per-chunk flag; write x0 splits
// only if own chunk is nonzero (gemm zero-masks unwritten chunks).
__global__ __launch_bounds__(256) void presplit_kernel(
    const float* __restrict__ x, const float* __restrict__ x0,
    unsigned short* __restrict__ Ah, unsigned short* __restrict__ Al,
    int* __restrict__ flags) {
    const int z = blockIdx.y;
    const int i = blockIdx.x;
    const int t = threadIdx.x;
    if (z == 0) {
        presplit_blk(x, Ah, Al, i, t);
        return;
    }
    // z == 1: flag pass (32 KB chunk, L1-hot for the optional second pass)
    __shared__ int snz[4];
    const int w = t >> 6, lane = t & 63;
    const int kg = i * 8 + (t & 7);
    int tnz = 0;
#pragma unroll
    for (int r = 0; r < 4; ++r) {
        const int m = (t >> 3) + r * 32;
        const float4* src = (const float4*)(x0 + (size_t)m * FF + kg * 8);
        const float4 a = src[0], b = src[1];
        tnz |= (a.x != 0.f) | (a.y != 0.f) | (a.z != 0.f) | (a.w != 0.f)
             | (b.x != 0.f) | (b.y != 0.f) | (b.z != 0.f) | (b.w != 0.f);
    }
    const int wnz = __any(tnz != 0) ? 1 : 0;
    if (lane == 0) snz[w] = wnz;
    __syncthreads();
    const int bnz = snz[0] | snz[1] | snz[2] | snz[3];
    if (t == 0) flags[i] = bnz;
    if (bnz) {
        const size_t zoff = (size_t)NKG * BB * 8;
        presplit_blk(x0, Ah + zoff, Al + zoff, i, t);
    }
}

// ---------------------------------------------------------------------------
// Split-precision MFMA GEMM partials: P[z*SK+kc] = X_z[:, kchunk] @ W1[kchunk, :].
// Tile 128x64, BK=32, 8 waves (512 threads, 16 rows/wave). A reg-direct
// (1 ahead, zero-masked per chunk for z=1); B fp32 prefetch 4 deep (4/thread)
// -> cvt_pk bsplit -> 16 KB dbuf LDS. Barrier drains LDS only.
__global__ __launch_bounds__(512, 4) void mfma_gemm_kernel(
    const unsigned short* __restrict__ Ah, const unsigned short* __restrict__ Al,
    const float* __restrict__ W1, float* __restrict__ P,
    const int* __restrict__ flags, int SK, int KC, int NIT) {
    const int z = blockIdx.y;
    if (z == 1 && !read_nz(flags)) return;

    // XCD-aware bijective swizzle (gridDim.x always % 8 == 0 here).
    const int nwg = gridDim.x;
    const int bx  = blockIdx.x;
    const int wg  = (bx & 7) * (nwg >> 3) + (bx >> 3);
    const int ct  = wg & 31;   // column tile (64 cols)
    const int kc  = wg >> 5;   // split-K chunk

    const int t   = threadIdx.x;
    const int w   = t >> 6;    // wave 0..7 (16 rows each)
    const int l   = t & 63;
    const int kgl = l >> 4;    // frag k-group 0..3
    const int li  = l & 15;

    __shared__ unsigned short lds[2][4096];  // [buf][Bh 2048 | Bl 2048]

    const size_t zoffA = (size_t)z * NKG * BB * 8;
    const unsigned short* APH = Ah + zoffA;
    const unsigned short* APL = Al + zoffA;
    const bool zchk = (z == 1);

    f32x4 acc[4];
#pragma unroll
    for (int nt = 0; nt < 4; ++nt) acc[nt] = (f32x4)0.f;

    const int kbase = kc * KC;
    const int kg0   = kbase >> 3;

    s16x8 ahE, alE, ahO, alO;
    auto loadA = [&](s16x8& ah, s16x8& al, int it) {
        const int kg = kg0 + it * 4 + kgl;
        if (zchk && flags[kg >> 3] == 0) {
            ah = (s16x8)0; al = (s16x8)0;
            return;
        }
        const size_t o = ((size_t)kg * BB + w * 16 + li) * 8;
        ah = *(const s16x8*)(APH + o);
        al = *(const s16x8*)(APL + o);
    };

    // B staging: thread t owns rows w*4..w*4+3 (k within chunk), col l.
    auto stageB_load = [&](int it, float* v) {
        const float* src = W1 + (size_t)(kbase + it * 32 + w * 4) * HH + ct * 64 + l;
#pragma unroll
        for (int j = 0; j < 4; ++j) v[j] = src[(size_t)j * HH];
    };
    // LDS element layout [kg 0..3][col 0..63][kin 0..7]; this thread's 4
    // values land contiguously: kg = w>>1, kin = (w&1)*4 + j.
    auto stageB_write = [&](int buf, const float* v) {
        u16x4 hv, lv;
#pragma unroll
        for (int j = 0; j < 4; ++j) {
            unsigned short h, lo;
            bsplit(v[j], h, lo);
            hv[j] = h; lv[j] = lo;
        }
        unsigned short* d = &lds[buf][(((w >> 1) * 64 + l) * 8) + (w & 1) * 4];
        *(u16x4*)(d)        = hv;
        *(u16x4*)(d + 2048) = lv;
    };
    auto computeR = [&](const s16x8& ah, const s16x8& al, int buf) {
        const unsigned short* L = lds[buf];
#pragma unroll
        for (int nt = 0; nt < 4; ++nt) {
            const int no = (kgl * 64 + nt * 16 + li) * 8;
            const s16x8 fbh = *(const s16x8*)&L[no];
            const s16x8 fbl = *(const s16x8*)&L[2048 + no];
            acc[nt] = __builtin_amdgcn_mfma_f32_16x16x32_bf16(ah, fbh, acc[nt], 0, 0, 0);
            acc[nt] = __builtin_amdgcn_mfma_f32_16x16x32_bf16(ah, fbl, acc[nt], 0, 0, 0);
            acc[nt] = __builtin_amdgcn_mfma_f32_16x16x32_bf16(al, fbh, acc[nt], 0, 0, 0);
        }
    };

    // Prologue: A(0); B(0) staged to buf0; B(1..3) in flight (depth 4).
    float bv0[4], bv1[4], bv2[4], bv3[4];
    loadA(ahE, alE, 0);
    stageB_load(0, bv0);
    stageB_write(0, bv0);
    stageB_load(1, bv1);
    stageB_load(2, bv2);
    stageB_load(3, bv3);
    barrier_lds();

    // 4-phase static unroll. Phase p (iter i = it+p):
    //   issue B-load(i+4) into slot p (freed by last phase's LDS write),
    //   A-load(i+1), compute(i) from buf p&1, LDS-write slot (p+1)&3 -> buf (p+1)&1.
    // NIT divisible by 4 for all SK in {16,8,4,2,1}.
#define GPHASE(p, bvCur, bvNext, aCurH, aCurL, aNxtH, aNxtL)                  \
    {                                                                         \
        if (it + 4 + (p) < NIT) stageB_load(it + 4 + (p), bvCur);             \
        if (it + (p) + 1 < NIT) loadA(aNxtH, aNxtL, it + (p) + 1);            \
        computeR(aCurH, aCurL, (p) & 1);                                      \
        if (it + (p) + 1 < NIT) stageB_write(((p) + 1) & 1, bvNext);          \
        barrier_lds();                                                        \
    }

    for (int it = 0; it < NIT; it += 4) {
        GPHASE(0, bv0, bv1, ahE, alE, ahO, alO)
        GPHASE(1, bv1, bv2, ahO, alO, ahE, alE)
        GPHASE(2, bv2, bv3, ahE, alE, ahO, alO)
        GPHASE(3, bv3, bv0, ahO, alO, ahE, alE)
    }
#undef GPHASE

    float* dst = P + (size_t)(z * SK + kc) * BH;
    const int r0 = w * 16 + (l >> 4) * 4;
    const int c0 = ct * 64 + li;
#pragma unroll
    for (int nt = 0; nt < 4; ++nt)
#pragma unroll
        for (int r = 0; r < 4; ++r)
            dst[(size_t)(r0 + r) * HH + c0 + nt * 16] = acc[nt][r];
}

// ---------------------------------------------------------------------------
// Scalar deterministic bisect for the linear (x0==0) case: f(c) = c*S - tau.
__device__ __forceinline__ void solve_linear(float S, float& c, bool& done) {
    const bool inside = (S - TAU_F <= 0.f);
    float a = 0.f, bh = 1.f;
    c = 1.f; done = inside;
    for (int it = 0; it < 30; ++it) {
        const float cm = 0.5f * (a + bh);
        const float v = cm * S - TAU_F;
        const bool upd  = !done;
        const bool hit  = upd && (v >= -THR_F) && (v < 0.f);
        const bool go_a = upd && (v < 0.f) && !hit;
        const bool go_b = upd && (v >= 0.f);
        a  = go_a ? cm : a;
        bh = go_b ? cm : bh;
        c  = upd  ? cm : c;
        done = done || hit;
    }
    c = inside ? 1.f : c;
}

// ---------------------------------------------------------------------------
// Fused tail, redundant-solve wide: 256 blocks x 512 threads. Block i owns
// sample b = i>>1 and half-row (i&1). Both blocks of a sample compute the
// IDENTICAL fixed-order reduction -> identical c (deterministic); each writes
// its half-row. Doubles the P read, but P is L3-hot; all 256 CUs busy.
__global__ __launch_bounds__(512) void bisect_write_kernel(
    const float* __restrict__ P, const float* __restrict__ w2,
    const float* __restrict__ x, const float* __restrict__ x0,
    const int* __restrict__ flags, float* __restrict__ out, int SK) {
    const int b    = blockIdx.x >> 1;
    const int half = blockIdx.x & 1;
    const int t = threadIdx.x;
    const int w = t >> 6;
    const int lane = t & 63;
    __shared__ float red[8];
    const bool nz = read_nz(flags);

    // Fixed-order split-K reduce: thread t owns 4 h-cols (one float4).
    const f32x4* P1 = (const f32x4*)(P + (size_t)b * HH) + t;
    f32x4 u1 = (f32x4)0.f;
    for (int kc = 0; kc < SK; ++kc) {           // fixed order: deterministic
        const f32x4 v = P1[(size_t)kc * (BH / 4)];
        u1.x += v.x; u1.y += v.y; u1.z += v.z; u1.w += v.w;
    }
    const f32x4 wv = ((const f32x4*)w2)[t];

    auto blockReduce = [&](float v) -> float {
#pragma unroll
        for (int off = 32; off > 0; off >>= 1) v += __shfl_xor(v, off);
        if (lane == 0) red[w] = v;
        __syncthreads();
        float s = 0.f;
#pragma unroll
        for (int i = 0; i < 8; ++i) s += red[i];   // fixed order, uniform
        __syncthreads();
        return s;
    };

    float c = 1.f;
    bool done = false;
    if (!nz) {
        float p = fmaxf(u1.x, 0.f) * wv.x;
        p = fmaf(fmaxf(u1.y, 0.f), wv.y, p);
        p = fmaf(fmaxf(u1.z, 0.f), wv.z, p);
        p = fmaf(fmaxf(u1.w, 0.f), wv.w, p);
        const float S = blockReduce(p);
        solve_linear(S, c, done);
    } else {
        const f32x4* P0 = (const f32x4*)(P + (size_t)(SK * BH) + (size_t)b * HH) + t;
        f32x4 u0 = (f32x4)0.f;
        for (int kc = 0; kc < SK; ++kc) {
            const f32x4 v = P0[(size_t)kc * (BH / 4)];
            u0.x += v.x; u0.y += v.y; u0.z += v.z; u0.w += v.w;
        }
        f32x4 dd;
        dd.x = u1.x - u0.x; dd.y = u1.y - u0.y;
        dd.z = u1.z - u0.z; dd.w = u1.w - u0.w;
        auto feval = [&](float cc) -> float {
            float p = fmaxf(fmaf(cc, dd.x, u0.x), 0.f) * wv.x;
            p = fmaf(fmaxf(fmaf(cc, dd.y, u0.y), 0.f), wv.y, p);
            p = fmaf(fmaxf(fmaf(cc, dd.z, u0.z), 0.f), wv.z, p);
            p = fmaf(fmaxf(fmaf(cc, dd.w, u0.w), 0.f), wv.w, p);
            return blockReduce(p) - TAU_F;
        };
        const float f1 = feval(1.f);
        const bool inside = (f1 <= 0.f);
        float a = 0.f, bh = 1.f;
        done = inside;
        for (int it = 0; it < 30; ++it) {
            const float cm = 0.5f * (a + bh);
            const float v = feval(cm);
            const bool upd  = !done;
            const bool hit  = upd && (v >= -THR_F) && (v < 0.f);
            const bool go_a = upd && (v < 0.f) && !hit;
            const bool go_b = upd && (v >= 0.f);
            a  = go_a ? cm : a;
            bh = go_b ? cm : bh;
            c  = upd  ? cm : c;
            done = done || hit;
        }
        c = inside ? 1.f : c;
    }

    // Write half-row (uniform branches). Half = 1536 f4; 512 thr x 3 f4.
    const float nanv = __int_as_float(0x7fc00000);
    const int base = half * 1536;
    const float4* xr  = (const float4*)(x  + (size_t)b * FF) + base;
    const float4* x0r = (const float4*)(x0 + (size_t)b * FF) + base;
    float4* orow = (float4*)(out + (size_t)b * FF) + base;
    if (!done) {
        float4 o; o.x = o.y = o.z = o.w = nanv;
#pragma unroll
        for (int k2 = 0; k2 < 3; ++k2) orow[t + 512 * k2] = o;
    } else if (!nz) {
#pragma unroll
        for (int k2 = 0; k2 < 3; ++k2) {
            const int i = t + 512 * k2;
            float4 xv = xr[i], o;
            o.x = c * xv.x; o.y = c * xv.y; o.z = c * xv.z; o.w = c * xv.w;
            orow[i] = o;
        }
    } else {
#pragma unroll
        for (int k2 = 0; k2 < 3; ++k2) {
            const int i = t + 512 * k2;
            float4 xv = xr[i], zv = x0r[i], o;
            o.x = fmaf(c, xv.x - zv.x, zv.x);
            o.y = fmaf(c, xv.y - zv.y, zv.y);
            o.z = fmaf(c, xv.z - zv.z, zv.z);
            o.w = fmaf(c, xv.w - zv.w, zv.w);
            orow[i] = o;
        }
    }
}

// ---------------------------------------------------------------------------
// Fallback path helpers (small workspace only).
__global__ __launch_bounds__(256) void zflags_kernel(
    const float4* __restrict__ x0, int* __restrict__ flags) {
    const int t = threadIdx.x;
    const int w = t >> 6, lane = t & 63;
    __shared__ int snz[4];
    int tnz = 0;
    const int base = blockIdx.x * 2048 + t;
#pragma unroll
    for (int j = 0; j < 8; ++j) {
        float4 v = x0[base + 256 * j];
        tnz |= (v.x != 0.f) | (v.y != 0.f) | (v.z != 0.f) | (v.w != 0.f);
    }
    const int wnz = __any(tnz != 0) ? 1 : 0;
    if (lane == 0) snz[w] = wnz;
    __syncthreads();
    if (t == 0) flags[blockIdx.x] = snz[0] | snz[1] | snz[2] | snz[3];
}

__global__ __launch_bounds__(256) void legacy_gemm_kernel(
    const float* __restrict__ x, const float* __restrict__ x0,
    const float* __restrict__ W1, float* __restrict__ P,
    const int* __restrict__ flags) {
    const int ct = blockIdx.x, z = blockIdx.z, t = threadIdx.x;
    if (z == 1 && !read_nz(flags)) return;
    const int cg = t & 7, rg = t >> 3;
    const int r0 = rg * 4, cc = ct * 64 + cg * 8;
    float acc[4][8];
#pragma unroll
    for (int i = 0; i < 4; ++i)
#pragma unroll
        for (int n = 0; n < 8; ++n) acc[i][n] = 0.f;
    const float* __restrict__ X = z ? x0 : x;
    for (int k = 0; k < FF; k += 4) {
        float xr[4][4];
#pragma unroll
        for (int i = 0; i < 4; ++i) {
            float4 v = *(const float4*)(X + (size_t)(r0 + i) * FF + k);
            xr[i][0] = v.x; xr[i][1] = v.y; xr[i][2] = v.z; xr[i][3] = v.w;
        }
        float wr[4][8];
#pragma unroll
        for (int j = 0; j < 4; ++j) {
            float4 a = *(const float4*)(W1 + (size_t)(k + j) * HH + cc);
            float4 b = *(const float4*)(W1 + (size_t)(k + j) * HH + cc + 4);
            wr[j][0] = a.x; wr[j][1] = a.y; wr[j][2] = a.z; wr[j][3] = a.w;
            wr[j][4] = b.x; wr[j][5] = b.y; wr[j][6] = b.z; wr[j][7] = b.w;
        }
#pragma unroll
        for (int j = 0; j < 4; ++j)
#pragma unroll
            for (int i = 0; i < 4; ++i)
#pragma unroll
                for (int n = 0; n < 8; ++n)
                    acc[i][n] = fmaf(xr[i][j], wr[j][n], acc[i][n]);
    }
    float* Pp = P + (size_t)z * BH;
#pragma unroll
    for (int i = 0; i < 4; ++i) {
        float4 o0, o1;
        o0.x = acc[i][0]; o0.y = acc[i][1]; o0.z = acc[i][2]; o0.w = acc[i][3];
        o1.x = acc[i][4]; o1.y = acc[i][5]; o1.z = acc[i][6]; o1.w = acc[i][7];
        *(float4*)(Pp + (size_t)(r0 + i) * HH + cc) = o0;
        *(float4*)(Pp + (size_t)(r0 + i) * HH + cc + 4) = o1;
    }
}

// ---------------------------------------------------------------------------
extern "C" void kernel_launch(void* const* d_in, const int* in_sizes, int n_in,
                              void* d_out, int out_size, void* d_ws, size_t ws_size,
                              hipStream_t stream) {
    const float* x0 = (const float*)d_in[0];
    const float* x  = (const float*)d_in[1];
    const float* W1 = (const float*)d_in[2];
    const float* w2 = (const float*)d_in[3];
    float* out = (float*)d_out;
    char* ws = (char*)d_ws;

    // ws: Ah | Al | flags(1KB) | P[2*SK][B][H]
    const size_t szA   = (size_t)2 * NKG * BB * 8 * sizeof(unsigned short); // 6291456
    const size_t offAl = szA;
    const size_t offFl = 2 * szA;
    const size_t offP  = offFl + 1024;

    int SK = 0;
    const int cand[5] = {SKD, 8, 4, 2, 1};   // NIT = FF/SK/32 divisible by 4 for all
    for (int i = 0; i < 5; ++i) {
        const size_t need = offP + (size_t)2 * cand[i] * BH * sizeof(float);
        if (ws_size >= need) { SK = cand[i]; break; }
    }

    if (SK > 0) {
        unsigned short* Ah = (unsigned short*)ws;
        unsigned short* Al = (unsigned short*)(ws + offAl);
        int*   flags = (int*)(ws + offFl);
        float* P     = (float*)(ws + offP);
        const int KC = FF / SK, NIT = KC / 32;

        presplit_kernel<<<dim3(NFLAGS, 2), 256, 0, stream>>>(x, x0, Ah, Al, flags);
        mfma_gemm_kernel<<<dim3(32 * SK, 2), 512, 0, stream>>>(Ah, Al, W1, P, flags, SK, KC, NIT);
        bisect_write_kernel<<<2 * BB, 512, 0, stream>>>(P, w2, x, x0, flags, out, SK);
    } else {
        // Low-memory fallback: fp32 VALU GEMM, SK=1 layout.
        float* P     = (float*)ws;
        int*   flags = (int*)(ws + (size_t)2 * BH * sizeof(float));
        zflags_kernel<<<NFLAGS, 256, 0, stream>>>((const float4*)x0, flags);
        legacy_gemm_kernel<<<dim3(32, 1, 2), 256, 0, stream>>>(x, x0, W1, P, flags);
        bisect_write_kernel<<<2 * BB, 512, 0, stream>>>(P, w2, x, x0, flags, out, 1);
    }
}